// Round 4
// baseline (491.458 us; speedup 1.0000x reference)
//
#include <hip/hip_runtime.h>

// Problem constants (from reference)
#define N_SPARSE 16
#define N_SEQ    2
#define N_DENSE  13
#define VOCAB    100000
#define EMBED    64
#define SEQ_LEN  50
#define BATCH    4096
#define N_FEAT   (N_SPARSE + N_SEQ)          // 18
#define OUT_COLS (N_FEAT * EMBED + N_DENSE)  // 1165

typedef float f4v __attribute__((ext_vector_type(4)));  // native vec for nontemporal

// Grid layout (blocks of 256 threads = 4 waves):
//  - [0, 1024):        L3 warm sweep of seq_tables (51.2 MB, linear -> efficient
//                      HBM reads; subsequent random seq gathers hit L3)
//  - [1024, 2048):     sparse gather + dense copy, one wave per b (4 b/block)
//                      (scheduled early so its cold random misses overlap the sweep)
//  - [2048, 4096):     sequence pooling, one wave per (sf, b)  (8192 waves)
#define SWEEP_BLOCKS 1024
#define SB_BLOCKS    (BATCH / 4)              // 1024
#define SEQ_BLOCKS   (N_SEQ * BATCH / 4)      // 2048
#define NBLOCKS      (SWEEP_BLOCKS + SB_BLOCKS + SEQ_BLOCKS)

#define SEQ_TAB_F4   (N_SEQ * VOCAB * EMBED / 4)   // 3,200,000 float4 elements

__global__ __launch_bounds__(256) void emb_kernel(
    const float* __restrict__ sparse_tables,  // [16,100000,64]
    const float* __restrict__ seq_tables,     // [2,100000,64]
    const float* __restrict__ dense_vals,     // [4096,13]
    const int* __restrict__ sparse_idx,       // [16,4096]
    const int* __restrict__ seq_idx,          // [2,4096,50]
    float* __restrict__ out)                  // [4096,1165]
{
    const int tid  = threadIdx.x;
    const int lane = tid & 63;
    const int wv   = tid >> 6;       // wave in block, 0..3
    const int g    = lane >> 4;      // lane group 0..3 (one row per group)
    const int l16  = lane & 15;      // position within group (float4 -> 64 cols)

    if (blockIdx.x < SWEEP_BLOCKS) {
        // ---------------- L3 warm sweep: linear read of seq_tables ----------------
        const f4v* p = reinterpret_cast<const f4v*>(seq_tables);
        const size_t base = (size_t)blockIdx.x * 256 + tid;
        float acc = 0.f;
        #pragma unroll
        for (int i = 0; i < 13; ++i) {
            const size_t e = base + (size_t)i * (SWEEP_BLOCKS * 256);
            if (e < SEQ_TAB_F4) {
                const f4v v = p[e];
                acc += v.x + v.y + v.z + v.w;
            }
        }
        asm volatile("" :: "v"(acc));   // keep loads live (rule #17)
        return;
    }

    if (blockIdx.x < SWEEP_BLOCKS + SB_BLOCKS) {
        // -------- sparse gather (16 features) + dense copy: one wave per b --------
        const int b = (blockIdx.x - SWEEP_BLOCKS) * 4 + wv;
        // lanes 0..15 fetch the 16 feature indices, broadcast via shfl
        int myidx16 = (lane < N_SPARSE) ? sparse_idx[lane * BATCH + b] : 0;

        f4v v[4];
        #pragma unroll
        for (int i = 0; i < 4; ++i) {
            const int f   = i * 4 + g;
            const int idx = __shfl(myidx16, f);
            // zero-reuse rows: nontemporal so they don't evict the warmed seq rows
            v[i] = __builtin_nontemporal_load(
                reinterpret_cast<const f4v*>(
                    sparse_tables + ((size_t)f * VOCAB + idx) * EMBED + 4 * l16));
        }
        float* ob = out + (size_t)b * OUT_COLS;
        #pragma unroll
        for (int i = 0; i < 4; ++i) {
            const int f = i * 4 + g;
            float* o = ob + f * EMBED + 4 * l16;
            o[0] = v[i].x; o[1] = v[i].y; o[2] = v[i].z; o[3] = v[i].w;
        }
        // dense passthrough: 13 floats per batch row
        if (lane < N_DENSE)
            ob[N_FEAT * EMBED + lane] = dense_vals[b * N_DENSE + lane];
        return;
    }

    // ---------------- sequence pooling: one wave per (sf, b) ----------------
    {
        const int w  = (blockIdx.x - SWEEP_BLOCKS - SB_BLOCKS) * 4 + wv;
        const int sf = w >> 12;               // 0 = sum pool, 1 = mean pool
        const int b  = w & (BATCH - 1);
        const int* ip = seq_idx + ((size_t)(sf * BATCH + b)) * SEQ_LEN;
        int myidx = (lane < SEQ_LEN) ? ip[lane] : 0;   // lane s holds index of row s
        const float* tab = seq_tables + (size_t)sf * VOCAB * EMBED;

        float ax = 0.f, ay = 0.f, az = 0.f, aw = 0.f;   // column sums
        float cx = 0.f, cy = 0.f, cz = 0.f, cw = 0.f;   // nonzero counts

        // 48 rows: 12 iterations x 4 rows (one per lane group), float4/lane.
        #pragma unroll
        for (int i = 0; i < 12; ++i) {
            const int row = i * 4 + g;
            const int idx = __shfl(myidx, row);
            const float4 v = *reinterpret_cast<const float4*>(
                tab + (size_t)idx * EMBED + 4 * l16);
            ax += v.x; ay += v.y; az += v.z; aw += v.w;
            cx += (v.x != 0.f) ? 1.f : 0.f;
            cy += (v.y != 0.f) ? 1.f : 0.f;
            cz += (v.z != 0.f) ? 1.f : 0.f;
            cw += (v.w != 0.f) ? 1.f : 0.f;
        }
        // remainder rows 48,49 handled by groups 0,1 (shfl done while all active)
        {
            const int row = 48 + g;
            const int idx = __shfl(myidx, (row < SEQ_LEN) ? row : 0);
            if (row < SEQ_LEN) {
                const float4 v = *reinterpret_cast<const float4*>(
                    tab + (size_t)idx * EMBED + 4 * l16);
                ax += v.x; ay += v.y; az += v.z; aw += v.w;
                cx += (v.x != 0.f) ? 1.f : 0.f;
                cy += (v.y != 0.f) ? 1.f : 0.f;
                cz += (v.z != 0.f) ? 1.f : 0.f;
                cw += (v.w != 0.f) ? 1.f : 0.f;
            }
        }

        // reduce partial sums across the 4 lane groups (xor 16, then 32)
        ax += __shfl_xor(ax, 16); ax += __shfl_xor(ax, 32);
        ay += __shfl_xor(ay, 16); ay += __shfl_xor(ay, 32);
        az += __shfl_xor(az, 16); az += __shfl_xor(az, 32);
        aw += __shfl_xor(aw, 16); aw += __shfl_xor(aw, 32);
        if (sf == 1) {  // wave-uniform branch
            cx += __shfl_xor(cx, 16); cx += __shfl_xor(cx, 32);
            cy += __shfl_xor(cy, 16); cy += __shfl_xor(cy, 32);
            cz += __shfl_xor(cz, 16); cz += __shfl_xor(cz, 32);
            cw += __shfl_xor(cw, 16); cw += __shfl_xor(cw, 32);
            ax = ax / (cx + 1e-16f);
            ay = ay / (cy + 1e-16f);
            az = az / (cz + 1e-16f);
            aw = aw / (cw + 1e-16f);
        }

        if (lane < 16) {
            float* o = out + (size_t)b * OUT_COLS + (N_SPARSE + sf) * EMBED + 4 * l16;
            o[0] = ax; o[1] = ay; o[2] = az; o[3] = aw;
        }
    }
}

extern "C" void kernel_launch(void* const* d_in, const int* in_sizes, int n_in,
                              void* d_out, int out_size, void* d_ws, size_t ws_size,
                              hipStream_t stream) {
    const float* sparse_tables = (const float*)d_in[0];
    const float* seq_tables    = (const float*)d_in[1];
    const float* dense_vals    = (const float*)d_in[2];
    const int*   sparse_idx    = (const int*)d_in[3];
    const int*   seq_idx       = (const int*)d_in[4];
    float*       out           = (float*)d_out;

    emb_kernel<<<dim3(NBLOCKS), dim3(256), 0, stream>>>(
        sparse_tables, seq_tables, dense_vals, sparse_idx, seq_idx, out);
}